// Round 5
// baseline (20.204 us; speedup 1.0000x reference)
//
#include <hip/hip_runtime.h>

// out[b,o] = max_i min(m[b,i], clamp(w[i,o],0,1)); B=128, I=2048, O=512.
// k0 (prep): clamp+cvt W -> fp16 TRANSPOSED [o][i] + cvt M -> fp16 into ws;
//            zero d_out. (2.5 MB ws)
// k1 (fuse): 512 blocks = 64 tiles(32x32) x K=8 i-ranges(256 i).
//            256 thr = 4 waves (wave = 8-col slice), lane = 2x2 outputs.
//            2 chunks x 128 i, double-buffered LDS (32 KB), 2 barriers.
//            Epilogue: atomicMax on fp32 bit patterns (all values >= 0).

typedef _Float16 h2 __attribute__((ext_vector_type(2)));
typedef _Float16 h4 __attribute__((ext_vector_type(4)));
typedef _Float16 h8 __attribute__((ext_vector_type(8)));

#define WT_OFF 0            // W16T [512 o][2048 i]
#define M_OFF  1048576      // M16  [128 b][2048 i]

__global__ __launch_bounds__(256)
void prep(const float* __restrict__ M, const float* __restrict__ W,
          _Float16* __restrict__ ws, float* __restrict__ out) {
    __shared__ float lds[512 * 9];          // 18 KB, stride 9 (transpose staging)
    const int t = threadIdx.x;
    const int bid = blockIdx.x;             // 256 blocks
    const int iB = bid & 3, oB = bid >> 2;  // W strip: 512 i x 8 o
    const int i0 = iB * 512, o0 = oB * 8;

    // stage W strip (clamp fused, once per element)
#pragma unroll
    for (int j = 0; j < 16; ++j) {
        int slot = j * 256 + t;
        int i = slot >> 3, o = slot & 7;
        float v = W[(i0 + i) * 512 + o0 + o];
        lds[i * 9 + o] = fminf(fmaxf(v, 0.f), 1.f);
    }
    __syncthreads();
    // read transposed, convert, store W16T coalesced in i
#pragma unroll
    for (int j = 0; j < 2; ++j) {
        int slot = j * 256 + t;
        int o = slot & 7, c8 = (slot >> 3) & 63;
        h8 r;
#pragma unroll
        for (int e = 0; e < 8; ++e)
            r[e] = (_Float16)lds[(c8 * 8 + e) * 9 + o];
        *(h8*)&ws[WT_OFF + (o0 + o) * 2048 + i0 + c8 * 8] = r;
    }
    // M convert: 1 float4 per thread (256 blocks x 1024 = 128*2048)
    {
        int idx = bid * 1024 + t * 4;
        float4 v = *(const float4*)&M[idx];
        h4 r = {(_Float16)v.x, (_Float16)v.y, (_Float16)v.z, (_Float16)v.w};
        *(h4*)&ws[M_OFF + idx] = r;
    }
    // zero d_out (256 blocks x 256 = 65536)
    out[bid * 256 + t] = 0.f;
}

__device__ __forceinline__ void stage_write(_Float16* buf, int row, int c8,
                                            uint4 vm, uint4 vw) {
    // lm at [0], lw at [4096]; both [32][128] h, h8-chunk XOR-swizzled by row&15
    *(uint4*)&buf[row * 128 + ((c8 ^ (row & 15)) << 3)] = vm;
    *(uint4*)&buf[4096 + row * 128 + ((c8 ^ (row & 15)) << 3)] = vw;
}

__global__ __launch_bounds__(256)
void fuse(const _Float16* __restrict__ ws, float* __restrict__ out) {
    const _Float16* WT  = ws + WT_OFF;     // [512][2048]
    const _Float16* M16 = ws + M_OFF;      // [128][2048]
    __shared__ _Float16 lds[2][8192];      // 2 x (lm 4096 | lw 4096) = 32 KB

    const int t = threadIdx.x;
    const int w = t >> 6, l = t & 63;
    const int lb = l >> 2, lc = l & 3;     // lane: rows 2lb+{0,1}, cols w*8+2lc+{0,1}
    const int bid = blockIdx.x;
    const int bt = bid >> 7, ot = (bid >> 3) & 15, k = bid & 7; // bid&7=k -> XCD locality
    const int b0 = bt * 32, o0 = ot * 32, i0 = k * 256;

    const int r0 = t >> 4, c80 = t & 15;   // this thread's staging slots (rows r0, r0+16)

    // ---- load chunk 0 ----
    uint4 m0a = *(const uint4*)&M16[(b0 + r0) * 2048 + i0 + c80 * 8];
    uint4 m0b = *(const uint4*)&M16[(b0 + r0 + 16) * 2048 + i0 + c80 * 8];
    uint4 w0a = *(const uint4*)&WT [(o0 + r0) * 2048 + i0 + c80 * 8];
    uint4 w0b = *(const uint4*)&WT [(o0 + r0 + 16) * 2048 + i0 + c80 * 8];
    stage_write(&lds[0][0], r0, c80, m0a, w0a);
    stage_write(&lds[0][0], r0 + 16, c80, m0b, w0b);
    // ---- issue chunk 1 loads (land during compute of chunk 0) ----
    uint4 m1a = *(const uint4*)&M16[(b0 + r0) * 2048 + i0 + 128 + c80 * 8];
    uint4 m1b = *(const uint4*)&M16[(b0 + r0 + 16) * 2048 + i0 + 128 + c80 * 8];
    uint4 w1a = *(const uint4*)&WT [(o0 + r0) * 2048 + i0 + 128 + c80 * 8];
    uint4 w1b = *(const uint4*)&WT [(o0 + r0 + 16) * 2048 + i0 + 128 + c80 * 8];
    __syncthreads();

    h2 acc[2][2];
#pragma unroll
    for (int rr = 0; rr < 2; ++rr)
#pragma unroll
        for (int cc = 0; cc < 2; ++cc) acc[rr][cc] = (h2)0;  // min>=0: exact

#define COMPUTE(BUF)                                                          \
    _Pragma("unroll")                                                         \
    for (int g = 0; g < 16; ++g) {                                            \
        h8 mf[2], wf[2];                                                      \
        _Pragma("unroll")                                                     \
        for (int rr = 0; rr < 2; ++rr) {                                      \
            int row = 2 * lb + rr;                                            \
            mf[rr] = *(const h8*)&lds[BUF][row * 128 + ((g ^ (row & 15)) << 3)]; \
            int col = w * 8 + 2 * lc + rr;                                    \
            wf[rr] = *(const h8*)&lds[BUF][4096 + col * 128 + ((g ^ (col & 15)) << 3)]; \
        }                                                                     \
        _Pragma("unroll")                                                     \
        for (int rr = 0; rr < 2; ++rr)                                        \
            _Pragma("unroll")                                                 \
            for (int cc = 0; cc < 2; ++cc) {                                  \
                h8 m8 = __builtin_elementwise_min(mf[rr], wf[cc]);            \
                h2 a = __builtin_elementwise_max(                             \
                           __builtin_shufflevector(m8, m8, 0, 1),             \
                           __builtin_shufflevector(m8, m8, 2, 3));            \
                h2 b = __builtin_elementwise_max(                             \
                           __builtin_shufflevector(m8, m8, 4, 5),             \
                           __builtin_shufflevector(m8, m8, 6, 7));            \
                acc[rr][cc] = __builtin_elementwise_max(                      \
                                  acc[rr][cc], __builtin_elementwise_max(a, b)); \
            }                                                                 \
    }

    COMPUTE(0)
    // stage chunk 1 into buf 1 (disjoint from buf 0: no barrier needed before)
    stage_write(&lds[1][0], r0, c80, m1a, w1a);
    stage_write(&lds[1][0], r0 + 16, c80, m1b, w1b);
    __syncthreads();
    COMPUTE(1)
#undef COMPUTE

    // ---- epilogue: i-parity merge + deterministic atomicMax (nonneg floats) ----
#pragma unroll
    for (int rr = 0; rr < 2; ++rr)
#pragma unroll
        for (int cc = 0; cc < 2; ++cc) {
            h2 e = acc[rr][cc];
            float v = fmaxf((float)e.x, (float)e.y);
            int row = b0 + 2 * lb + rr;
            int col = o0 + w * 8 + 2 * lc + cc;
            atomicMax((unsigned int*)&out[row * 512 + col], __float_as_uint(v));
        }
}

extern "C" void kernel_launch(void* const* d_in, const int* in_sizes, int n_in,
                              void* d_out, int out_size, void* d_ws, size_t ws_size,
                              hipStream_t stream) {
    const float* M = (const float*)d_in[0];   // [128][2048]
    const float* W = (const float*)d_in[1];   // [2048][512]
    float* out = (float*)d_out;               // [128][512]
    _Float16* ws = (_Float16*)d_ws;           // 2.5 MiB used

    prep<<<dim3(256), dim3(256), 0, stream>>>(M, W, ws, out);
    fuse<<<dim3(512), dim3(256), 0, stream>>>(ws, out);
}